// Round 1
// baseline (12119.669 us; speedup 1.0000x reference)
//
#include <hip/hip_runtime.h>
#include <hip/hip_bf16.h>
#include <cstddef>

// ---------------------------------------------------------------------------
// MIGCL graph autoencoder forward.
//   z  = elu(bn(feat@eW0)); z = elu(bn(z@eW1))
//   per graph: s = z@gW1; h = relu(scatter(w*s[src]->dst) + gb1)
//              s2 = h@gW2; emb_g = scatter(w*s2[src]->dst) + gb2
//   attention softmax over 2 views -> emb
//   d = elu(bn(emb@dW0)); de = sigmoid(bn(d@dW1))
// Outputs concat: femb[N*128] semb[N*128] de[N*3000] emb[N*128]
//
// Scratch: z0/z1/s/agg live inside d_out's `de` region (written last).
//          decoder hidden `d` lives in d_ws (needs N*512*4 = 102.4 MB).
// ---------------------------------------------------------------------------

typedef __bf16 bf16x8 __attribute__((ext_vector_type(8)));
typedef float  f32x4  __attribute__((ext_vector_type(4)));

#define LDSP 40   // 32 k + 8 pad (bf16) -> 80B row stride, 16B aligned, 2-way bank alias only

__device__ __forceinline__ float elu_f(float x) {
    return x > 0.f ? x : (__expf(x) - 1.f);
}

// C = act(bn(A@B + bias)); A[M,K] fp32, B[K,N] fp32, C[M,N] fp32.
// ACT: 0 = none, 1 = BN+ELU, 2 = BN+sigmoid. bf16 MFMA 16x16x32, 64x64 tile.
template<int ACT, bool HAS_BIAS, bool HAS_BN>
__global__ __launch_bounds__(256)
void gemm_fused(const float* __restrict__ A, const float* __restrict__ B,
                const float* __restrict__ bias, const float* __restrict__ gamma,
                const float* __restrict__ beta, float* __restrict__ C,
                int M, int K, int N)
{
    __shared__ __align__(16) __bf16 As[64 * LDSP];   // [row][k]
    __shared__ __align__(16) __bf16 Bs[64 * LDSP];   // [n][k]  (transposed)

    const int t    = threadIdx.x;
    const int lane = t & 63;
    const int wv   = t >> 6;        // wave 0..3 -> rows wv*16..+16
    const int quad = lane >> 4;     // 0..3
    const int m16  = lane & 15;

    const int row0 = blockIdx.y * 64;
    const int col0 = blockIdx.x * 64;

    f32x4 acc[4];
#pragma unroll
    for (int i = 0; i < 4; ++i) acc[i] = (f32x4){0.f, 0.f, 0.f, 0.f};

    // staging maps
    const int ar = t >> 2;           // A row 0..63
    const int ak = (t & 3) << 3;     // A k 0,8,16,24
    const int bn = t & 63;           // B n 0..63
    const int bk = (t >> 6) << 3;    // B k 0,8,16,24
    const bool arow_ok = (row0 + ar) < M;
    const bool bcol_ok = (col0 + bn) < N;

    for (int k0 = 0; k0 < K; k0 += 32) {
        // ---- stage A tile (64x32), fp32 -> bf16 ----
        {
            const float* ap = A + (size_t)(row0 + ar) * K + (k0 + ak);
            bf16x8 v8;
            if (arow_ok && (k0 + ak + 8) <= K) {
                float4 u = *(const float4*)ap;
                float4 v = *(const float4*)(ap + 4);
                v8[0] = (__bf16)u.x; v8[1] = (__bf16)u.y;
                v8[2] = (__bf16)u.z; v8[3] = (__bf16)u.w;
                v8[4] = (__bf16)v.x; v8[5] = (__bf16)v.y;
                v8[6] = (__bf16)v.z; v8[7] = (__bf16)v.w;
            } else {
#pragma unroll
                for (int j = 0; j < 8; ++j) {
                    int kk = k0 + ak + j;
                    v8[j] = (arow_ok && kk < K) ? (__bf16)ap[j] : (__bf16)0.f;
                }
            }
            *(bf16x8*)&As[ar * LDSP + ak] = v8;
        }
        // ---- stage B tile transposed: Bs[n][k] <- B[k][n] ----
        {
            bf16x8 v8;
#pragma unroll
            for (int j = 0; j < 8; ++j) {
                int kk = k0 + bk + j;
                float v = (bcol_ok && kk < K) ? B[(size_t)kk * N + (col0 + bn)] : 0.f;
                v8[j] = (__bf16)v;
            }
            *(bf16x8*)&Bs[bn * LDSP + bk] = v8;
        }
        __syncthreads();

        // ---- MFMA: wave computes 16 rows x 64 cols ----
        bf16x8 a = *(const bf16x8*)&As[(wv * 16 + m16) * LDSP + quad * 8];
#pragma unroll
        for (int nt = 0; nt < 4; ++nt) {
            bf16x8 b = *(const bf16x8*)&Bs[(nt * 16 + m16) * LDSP + quad * 8];
            acc[nt] = __builtin_amdgcn_mfma_f32_16x16x32_bf16(a, b, acc[nt], 0, 0, 0);
        }
        __syncthreads();
    }

    // ---- epilogue: C/D layout col=lane&15, row=quad*4+reg (m89-verified) ----
    const float kBN = 0.99950037f;   // 1/sqrt(1 + 1e-3)
    const int orow = row0 + wv * 16 + quad * 4;
#pragma unroll
    for (int nt = 0; nt < 4; ++nt) {
        int gc = col0 + nt * 16 + m16;
        if (gc >= N) continue;
        float bi = HAS_BIAS ? bias[gc] : 0.f;
        float g  = HAS_BN ? gamma[gc] * kBN : 1.f;
        float bt = HAS_BN ? beta[gc] : 0.f;
#pragma unroll
        for (int r = 0; r < 4; ++r) {
            int gr = orow + r;
            if (gr >= M) continue;
            float x = acc[nt][r] + bi;
            if (HAS_BN) x = x * g + bt;
            if (ACT == 1) x = elu_f(x);
            else if (ACT == 2) x = 1.f / (1.f + __expf(-x));
            C[(size_t)gr * N + gc] = x;
        }
    }
}

// out[dst[e]] += w[e] * s[src[e]]  over C dims, float4-vectorized.
// lsh = log2(C/4); consecutive threads = consecutive dims of one edge (coalesced).
__global__ __launch_bounds__(256)
void scatter_add_kernel(const float* __restrict__ s, const int* __restrict__ src,
                        const int* __restrict__ dst, const float* __restrict__ w,
                        float* __restrict__ outb, int E, int C, int lsh)
{
    int t = blockIdx.x * blockDim.x + threadIdx.x;
    int total = E << lsh;
    if (t >= total) return;
    int e = t >> lsh;
    int c = (t & ((1 << lsh) - 1)) << 2;
    float ww = w[e];
    int sr = src[e], dr = dst[e];
    float4 v = *(const float4*)(s + (size_t)sr * C + c);
    float* op = outb + (size_t)dr * C + c;
    unsafeAtomicAdd(op + 0, v.x * ww);
    unsafeAtomicAdd(op + 1, v.y * ww);
    unsafeAtomicAdd(op + 2, v.z * ww);
    unsafeAtomicAdd(op + 3, v.w * ww);
}

// buf[i] = (relu?) max(buf[i] + b[i % C], 0) ; C power of 2
__global__ __launch_bounds__(256)
void bias_act_kernel(float* __restrict__ buf, const float* __restrict__ b,
                     int total, int cmask, int relu)
{
    int t = blockIdx.x * blockDim.x + threadIdx.x;
    if (t >= total) return;
    float v = buf[t] + b[t & cmask];
    if (relu) v = fmaxf(v, 0.f);
    buf[t] = v;
}

// attention over 2 views: beta = softmax([femb@aW, semb@aW]); emb = sum beta*view
// one wave per node, 2 dims per lane (EMB=128).
__global__ __launch_bounds__(256)
void attention_kernel(const float* __restrict__ femb, const float* __restrict__ semb,
                      const float* __restrict__ aW, float* __restrict__ emb, int Nn)
{
    int node = blockIdx.x * 4 + (threadIdx.x >> 6);
    int lane = threadIdx.x & 63;
    if (node >= Nn) return;
    const float2 f = *(const float2*)(femb + (size_t)node * 128 + lane * 2);
    const float2 s = *(const float2*)(semb + (size_t)node * 128 + lane * 2);
    const float2 a = *(const float2*)(aW + lane * 2);
    float pf = f.x * a.x + f.y * a.y;
    float ps = s.x * a.x + s.y * a.y;
#pragma unroll
    for (int off = 32; off; off >>= 1) {
        pf += __shfl_xor(pf, off);
        ps += __shfl_xor(ps, off);
    }
    float m = fmaxf(pf, ps);
    float ef = __expf(pf - m), es = __expf(ps - m);
    float inv = 1.f / (ef + es);
    float bf = ef * inv, bs = es * inv;
    float2 o;
    o.x = bf * f.x + bs * s.x;
    o.y = bf * f.y + bs * s.y;
    *(float2*)(emb + (size_t)node * 128 + lane * 2) = o;
}

extern "C" void kernel_launch(void* const* d_in, const int* in_sizes, int n_in,
                              void* d_out, int out_size, void* d_ws, size_t ws_size,
                              hipStream_t stream)
{
    const int NN = 50000, DIN = 3000, H0 = 512, H1 = 128, GH = 256, EMB = 128, D1 = 512;
    const int E = in_sizes[2];

    const float* feat = (const float*)d_in[0];
    const int*   fidx = (const int*)d_in[1];
    const float* fw   = (const float*)d_in[2];
    const int*   sidx = (const int*)d_in[3];
    const float* sw   = (const float*)d_in[4];
    const float* eW0  = (const float*)d_in[5];
    const float* eb0  = (const float*)d_in[6];
    const float* eg0  = (const float*)d_in[7];
    const float* ebt0 = (const float*)d_in[8];
    const float* eW1  = (const float*)d_in[9];
    const float* eb1  = (const float*)d_in[10];
    const float* eg1  = (const float*)d_in[11];
    const float* ebt1 = (const float*)d_in[12];
    const float* gW1  = (const float*)d_in[13];
    const float* gb1  = (const float*)d_in[14];
    const float* gW2  = (const float*)d_in[15];
    const float* gb2  = (const float*)d_in[16];
    const float* aW   = (const float*)d_in[17];
    const float* dW0  = (const float*)d_in[18];
    const float* db0  = (const float*)d_in[19];
    const float* dg0  = (const float*)d_in[20];
    const float* dbt0 = (const float*)d_in[21];
    const float* dW1  = (const float*)d_in[22];
    const float* db1  = (const float*)d_in[23];
    const float* dg1  = (const float*)d_in[24];
    const float* dbt1 = (const float*)d_in[25];

    float* out  = (float*)d_out;
    float* femb = out;
    float* semb = out + (size_t)NN * EMB;
    float* de   = out + (size_t)NN * EMB * 2;
    float* emb  = out + (size_t)NN * EMB * 2 + (size_t)NN * DIN;

    // scratch inside the (not-yet-written) de region: needs NN*1152 < NN*3000 floats
    float* z0 = de;                          // [NN,512]
    float* z1 = de + (size_t)NN * 512;       // [NN,128]
    float* sb = de + (size_t)NN * 640;       // [NN,256] (also reused as [NN,128])
    float* ag = de + (size_t)NN * 896;       // [NN,256]
    float* db = (float*)d_ws;                // [NN,512] decoder hidden (read while de written)

    dim3 blk(256);
    auto cdiv = [](int a, int b) { return (a + b - 1) / b; };

    // encoder
    gemm_fused<1, true, true><<<dim3(cdiv(H0, 64), cdiv(NN, 64)), blk, 0, stream>>>(
        feat, eW0, eb0, eg0, ebt0, z0, NN, DIN, H0);
    gemm_fused<1, true, true><<<dim3(cdiv(H1, 64), cdiv(NN, 64)), blk, 0, stream>>>(
        z0, eW1, eb1, eg1, ebt1, z1, NN, H0, H1);

    // two GCN branches (shared weights)
    for (int g = 0; g < 2; ++g) {
        const int*   idx    = g ? sidx : fidx;
        const float* w      = g ? sw : fw;
        float*       embout = g ? semb : femb;

        gemm_fused<0, false, false><<<dim3(cdiv(GH, 64), cdiv(NN, 64)), blk, 0, stream>>>(
            z1, gW1, nullptr, nullptr, nullptr, sb, NN, H1, GH);
        hipMemsetAsync(ag, 0, (size_t)NN * GH * sizeof(float), stream);
        scatter_add_kernel<<<cdiv(E * (GH / 4), 256), blk, 0, stream>>>(
            sb, idx, idx + E, w, ag, E, GH, 6);
        bias_act_kernel<<<cdiv(NN * GH, 256), blk, 0, stream>>>(
            ag, gb1, NN * GH, GH - 1, 1);

        gemm_fused<0, false, false><<<dim3(cdiv(EMB, 64), cdiv(NN, 64)), blk, 0, stream>>>(
            ag, gW2, nullptr, nullptr, nullptr, sb, NN, GH, EMB);
        hipMemsetAsync(embout, 0, (size_t)NN * EMB * sizeof(float), stream);
        scatter_add_kernel<<<cdiv(E * (EMB / 4), 256), blk, 0, stream>>>(
            sb, idx, idx + E, w, embout, E, EMB, 5);
        bias_act_kernel<<<cdiv(NN * EMB, 256), blk, 0, stream>>>(
            embout, gb2, NN * EMB, EMB - 1, 0);
    }

    // attention pooling -> emb
    attention_kernel<<<cdiv(NN, 4), blk, 0, stream>>>(femb, semb, aW, emb, NN);

    // decoder
    gemm_fused<1, true, true><<<dim3(cdiv(D1, 64), cdiv(NN, 64)), blk, 0, stream>>>(
        emb, dW0, db0, dg0, dbt0, db, NN, EMB, D1);
    gemm_fused<2, true, true><<<dim3(cdiv(DIN, 64), cdiv(NN, 64)), blk, 0, stream>>>(
        db, dW1, db1, dg1, dbt1, de, NN, D1, DIN);
}